// Round 2
// baseline (247.193 us; speedup 1.0000x reference)
//
#include <hip/hip_runtime.h>
#include <hip/hip_bf16.h>

#define BDIM 2
#define SDIM 2048
#define HDIM 16
#define DDIM 64
#define HID  1024
#define MDIM (BDIM * SDIM)  // 4096

typedef __attribute__((ext_vector_type(8))) short short8;
typedef __attribute__((ext_vector_type(4))) float f32x4;

__device__ __forceinline__ short f2bf(float f) {
    union { float f; unsigned int i; } x; x.f = f;
    unsigned int r = x.i + 0x7fffu + ((x.i >> 16) & 1u);
    return (short)(r >> 16);
}

// ---------------- convert f32 -> bf16 (8 elems/thread) ----------------
__global__ __launch_bounds__(256) void cvt_bf16(const float* __restrict__ in,
                                               short* __restrict__ out, int n) {
    int i = (blockIdx.x * 256 + threadIdx.x) * 8;
    if (i >= n) return;
    float4 a = *(const float4*)(in + i);
    float4 b = *(const float4*)(in + i + 4);
    short8 v;
    v[0] = f2bf(a.x); v[1] = f2bf(a.y); v[2] = f2bf(a.z); v[3] = f2bf(a.w);
    v[4] = f2bf(b.x); v[5] = f2bf(b.y); v[6] = f2bf(b.z); v[7] = f2bf(b.w);
    *(short8*)(out + i) = v;
}

// ------------- transpose 4 f32 weights [K][N] -> bf16 [N][K] -------------
__global__ __launch_bounds__(256) void transpose4(
    const float* __restrict__ w0, const float* __restrict__ w1,
    const float* __restrict__ w2, const float* __restrict__ w3,
    short* __restrict__ o0, short* __restrict__ o1,
    short* __restrict__ o2, short* __restrict__ o3)
{
    const float* src; short* dst;
    int z = blockIdx.z;
    if (z == 0)      { src = w0; dst = o0; }
    else if (z == 1) { src = w1; dst = o1; }
    else if (z == 2) { src = w2; dst = o2; }
    else             { src = w3; dst = o3; }
    __shared__ float t[64][65];
    int r0 = blockIdx.y * 64, c0 = blockIdx.x * 64;
    int rd_r = threadIdx.x >> 4, rd_c = (threadIdx.x & 15) * 4;
    #pragma unroll
    for (int it = 0; it < 4; it++) {
        int rr = rd_r + it * 16;
        float4 v = *(const float4*)(src + (size_t)(r0 + rr) * HID + c0 + rd_c);
        t[rr][rd_c + 0] = v.x; t[rr][rd_c + 1] = v.y;
        t[rr][rd_c + 2] = v.z; t[rr][rd_c + 3] = v.w;
    }
    __syncthreads();
    int or_ = threadIdx.x >> 3, oc8 = (threadIdx.x & 7) * 8;
    #pragma unroll
    for (int half = 0; half < 2; half++) {
        int dr = or_ + half * 32;
        short8 v;
        #pragma unroll
        for (int i = 0; i < 8; i++) v[i] = f2bf(t[oc8 + i][dr]);
        *(short8*)(dst + (size_t)(c0 + dr) * HID + r0 + oc8) = v;
    }
}

// ---------------- GEMM: out = X[M,1024](bf16) @ Wt(bf16,[N][K]) + bias(f32) ----
// mode 0/1: q/k with RoPE -> [B,H,S,D] bf16; mode 2: v -> [B,H,S,D] bf16
// mode 3: plain row-major [M,N] f32 (final proj)
__global__ __launch_bounds__(256) void gemm_bf16(
    const short* __restrict__ X,
    const short* __restrict__ Wt0,
    const float* __restrict__ b0, const float* __restrict__ b1, const float* __restrict__ b2,
    const float* __restrict__ cosb, const float* __restrict__ sinb,
    short* __restrict__ out0, float* __restrict__ outf,
    int modeBase)
{
    constexpr int LDK = 40;  // 80B row stride: 16B-aligned, spreads banks
    __shared__ __align__(16) short Asm[128 * LDK];
    __shared__ __align__(16) short Bsm[128 * LDK];
    int z = blockIdx.z;
    int mode = modeBase + z;
    const short* Wt = Wt0 + (size_t)z * HID * HID;
    const float* bias = (z == 0) ? b0 : (z == 1) ? b1 : b2;
    short* outp = out0 + (size_t)z * MDIM * HID;

    int tid = threadIdx.x;
    int lane = tid & 63, wave = tid >> 6;
    int wr = wave >> 1, wc = wave & 1;
    int m0 = blockIdx.x * 128, n0 = blockIdx.y * 128;
    int sr = tid >> 2, sc = (tid & 3) * 8;
    int lr = lane & 15, lg = lane >> 4;

    f32x4 acc[4][4] = {};

    for (int k0 = 0; k0 < HID; k0 += 32) {
        short8 a0  = *(const short8*)(X  + (size_t)(m0 + sr)      * HID + k0 + sc);
        short8 a1  = *(const short8*)(X  + (size_t)(m0 + sr + 64) * HID + k0 + sc);
        short8 w0v = *(const short8*)(Wt + (size_t)(n0 + sr)      * HID + k0 + sc);
        short8 w1v = *(const short8*)(Wt + (size_t)(n0 + sr + 64) * HID + k0 + sc);
        __syncthreads();
        *(short8*)(Asm + sr * LDK + sc) = a0;
        *(short8*)(Asm + (sr + 64) * LDK + sc) = a1;
        *(short8*)(Bsm + sr * LDK + sc) = w0v;
        *(short8*)(Bsm + (sr + 64) * LDK + sc) = w1v;
        __syncthreads();
        short8 af[4], bfr[4];
        #pragma unroll
        for (int m = 0; m < 4; m++)
            af[m] = *(const short8*)(Asm + (wr * 64 + m * 16 + lr) * LDK + lg * 8);
        #pragma unroll
        for (int n = 0; n < 4; n++)
            bfr[n] = *(const short8*)(Bsm + (wc * 64 + n * 16 + lr) * LDK + lg * 8);
        #pragma unroll
        for (int m = 0; m < 4; m++)
            #pragma unroll
            for (int n = 0; n < 4; n++)
                acc[m][n] = __builtin_amdgcn_mfma_f32_16x16x32_bf16(af[m], bfr[n], acc[m][n], 0, 0, 0);
    }

    #pragma unroll
    for (int m = 0; m < 4; m++) {
        #pragma unroll
        for (int n = 0; n < 4; n++) {
            #pragma unroll
            for (int j = 0; j < 4; j++) {
                int gr = m0 + wr * 64 + m * 16 + lg * 4 + j;
                int gc = n0 + wc * 64 + n * 16 + lr;
                float v = acc[m][n][j] + bias[gc];
                if (mode == 3) {
                    outf[(size_t)gr * HID + gc] = v;
                } else {
                    int bb = gr >> 11, s = gr & (SDIM - 1);
                    int h = gc >> 6, dd = gc & 63;
                    if (mode < 2) {
                        // RoPE: partner (even<->odd col) sits in lane^1
                        float p  = __shfl_xor(v, 1);
                        float cc = cosb[s * 32 + (dd >> 1)];
                        float ss = sinb[s * 32 + (dd >> 1)];
                        v = (dd & 1) ? (p * ss + v * cc) : (v * cc - p * ss);
                    }
                    outp[((size_t)((bb * HDIM + h) * SDIM + s)) * DDIM + dd] = f2bf(v);
                }
            }
        }
    }
}

// ---------------- causal flash attention ----------------
// Q,K,V: [B*H, S, D] bf16.  O: [B, S, H, D] bf16.
__global__ __launch_bounds__(256) void attn_fwd(
    const short* __restrict__ Q,
    const short* __restrict__ K,
    const short* __restrict__ V,
    short* __restrict__ O)
{
    __shared__ __align__(16) short Ks[64 * 72];
    __shared__ __align__(16) short Vs[64 * 64];
    __shared__ __align__(16) short Ps[4][16 * 72];
    int qb = blockIdx.x;
    int bh = blockIdx.y;
    int tid = threadIdx.x;
    int lane = tid & 63, wave = tid >> 6;
    int lr = lane & 15, lg = lane >> 4;
    const short* qbase = Q + ((size_t)bh * SDIM) * DDIM;
    const short* kbase = K + ((size_t)bh * SDIM) * DDIM;
    const short* vbase = V + ((size_t)bh * SDIM) * DDIM;

    int qrow = qb * 64 + wave * 16 + lr;
    short8 qf[2];
    qf[0] = *(const short8*)(qbase + (size_t)qrow * DDIM + lg * 8);
    qf[1] = *(const short8*)(qbase + (size_t)qrow * DDIM + 32 + lg * 8);

    float m_run[4], l_run[4];
    #pragma unroll
    for (int j = 0; j < 4; j++) { m_run[j] = -1e30f; l_run[j] = 0.f; }
    f32x4 oacc[4] = {};

    int sr_ = tid >> 3, sc_ = (tid & 7) * 8;
    int qr_g = qb * 64 + wave * 16 + lg * 4;

    for (int kt = 0; kt <= qb; kt++) {
        __syncthreads();
        {
            const short* kg = kbase + (size_t)(kt * 64) * DDIM;
            const short* vg = vbase + (size_t)(kt * 64) * DDIM;
            short8 kv0 = *(const short8*)(kg + (size_t)sr_ * DDIM + sc_);
            short8 kv1 = *(const short8*)(kg + (size_t)(sr_ + 32) * DDIM + sc_);
            short8 vv0 = *(const short8*)(vg + (size_t)sr_ * DDIM + sc_);
            short8 vv1 = *(const short8*)(vg + (size_t)(sr_ + 32) * DDIM + sc_);
            *(short8*)(Ks + sr_ * 72 + sc_) = kv0;
            *(short8*)(Ks + (sr_ + 32) * 72 + sc_) = kv1;
            *(short8*)(Vs + sr_ * 64 + sc_) = vv0;
            *(short8*)(Vs + (sr_ + 32) * 64 + sc_) = vv1;
        }
        __syncthreads();

        f32x4 sf[4] = {};
        #pragma unroll
        for (int n = 0; n < 4; n++) {
            #pragma unroll
            for (int ks = 0; ks < 2; ks++) {
                short8 kf = *(const short8*)(Ks + (n * 16 + lr) * 72 + ks * 32 + lg * 8);
                sf[n] = __builtin_amdgcn_mfma_f32_16x16x32_bf16(qf[ks], kf, sf[n], 0, 0, 0);
            }
        }

        #pragma unroll
        for (int j = 0; j < 4; j++) {
            float sv[4];
            float mx = -1e30f;
            #pragma unroll
            for (int n = 0; n < 4; n++) {
                float s = sf[n][j] * 0.125f;
                int kv_g = kt * 64 + n * 16 + lr;
                if (kv_g > qr_g + j) s = -1e30f;  // causal mask (only diag tile triggers)
                sv[n] = s;
                mx = fmaxf(mx, s);
            }
            #pragma unroll
            for (int off = 1; off < 16; off <<= 1) mx = fmaxf(mx, __shfl_xor(mx, off));
            float mnew = fmaxf(m_run[j], mx);
            float scl = __expf(m_run[j] - mnew);
            float lsum = 0.f;
            #pragma unroll
            for (int n = 0; n < 4; n++) {
                float p = __expf(sv[n] - mnew);
                sv[n] = p;
                lsum += p;
            }
            #pragma unroll
            for (int off = 1; off < 16; off <<= 1) lsum += __shfl_xor(lsum, off);
            l_run[j] = l_run[j] * scl + lsum;
            m_run[j] = mnew;
            #pragma unroll
            for (int n = 0; n < 4; n++) {
                oacc[n][j] *= scl;
                Ps[wave][(lg * 4 + j) * 72 + n * 16 + lr] = f2bf(sv[n]);
            }
        }
        __syncthreads();

        #pragma unroll
        for (int ks = 0; ks < 2; ks++) {
            short8 pf = *(const short8*)(&Ps[wave][lr * 72 + ks * 32 + lg * 8]);
            #pragma unroll
            for (int n = 0; n < 4; n++) {
                short8 vf;
                #pragma unroll
                for (int i = 0; i < 8; i++)
                    vf[i] = Vs[(ks * 32 + lg * 8 + i) * 64 + n * 16 + lr];
                oacc[n] = __builtin_amdgcn_mfma_f32_16x16x32_bf16(pf, vf, oacc[n], 0, 0, 0);
            }
        }
    }

    int b = bh >> 4, h = bh & 15;
    #pragma unroll
    for (int n = 0; n < 4; n++) {
        #pragma unroll
        for (int j = 0; j < 4; j++) {
            int s = qb * 64 + wave * 16 + lg * 4 + j;
            int dd = n * 16 + lr;
            float v = oacc[n][j] / l_run[j];
            O[(((size_t)(b * SDIM + s) * HDIM) + h) * DDIM + dd] = f2bf(v);
        }
    }
}

extern "C" void kernel_launch(void* const* d_in, const int* in_sizes, int n_in,
                              void* d_out, int out_size, void* d_ws, size_t ws_size,
                              hipStream_t stream) {
    const float* x  = (const float*)d_in[0];
    const float* Wq = (const float*)d_in[1];
    const float* bq = (const float*)d_in[2];
    const float* Wk = (const float*)d_in[3];
    const float* bk = (const float*)d_in[4];
    const float* Wv = (const float*)d_in[5];
    const float* bv = (const float*)d_in[6];
    const float* Wo = (const float*)d_in[7];
    const float* bo = (const float*)d_in[8];
    // d_in[9] = mask (causal; computed analytically in-kernel)
    const float* fc = (const float*)d_in[10];
    const float* fs = (const float*)d_in[11];
    float* out = (float*)d_out;
    short* ws  = (short*)d_ws;

    const size_t MM = (size_t)HID * HID;       // 1M elements
    short* xb     = ws;                        // 4*MM  bf16 [M,K]
    short* wt_qkv = ws + 4 * MM;               // 3*MM
    short* wot    = ws + 7 * MM;               // 1*MM
    short* qt     = ws + 8 * MM;               // 4*MM  [B,H,S,D]
    short* ktb    = ws + 12 * MM;              // 4*MM
    short* vtb    = ws + 16 * MM;              // 4*MM
    short* ao     = ws + 20 * MM;              // 4*MM  [B,S,H,D]

    cvt_bf16<<<dim3((MDIM * HID) / (256 * 8)), 256, 0, stream>>>(x, xb, MDIM * HID);
    transpose4<<<dim3(16, 16, 4), 256, 0, stream>>>(Wq, Wk, Wv, Wo,
                                                    wt_qkv, wt_qkv + MM, wt_qkv + 2 * MM, wot);
    gemm_bf16<<<dim3(MDIM / 128, HID / 128, 3), 256, 0, stream>>>(
        xb, wt_qkv, bq, bk, bv, fc, fs, qt, nullptr, 0);
    attn_fwd<<<dim3(SDIM / 64, BDIM * HDIM), 256, 0, stream>>>(qt, ktb, vtb, ao);
    gemm_bf16<<<dim3(MDIM / 128, HID / 128, 1), 256, 0, stream>>>(
        ao, wot, bo, bo, bo, fc, fs, nullptr, out, 3);
}

// Round 3
// 214.053 us; speedup vs baseline: 1.1548x; 1.1548x over previous
//
#include <hip/hip_runtime.h>
#include <hip/hip_bf16.h>

#define BDIM 2
#define SDIM 2048
#define HDIM 16
#define DDIM 64
#define HID  1024
#define MDIM (BDIM * SDIM)  // 4096

typedef __attribute__((ext_vector_type(8))) short short8;
typedef __attribute__((ext_vector_type(4))) short short4v;
typedef __attribute__((ext_vector_type(4))) float f32x4;

__device__ __forceinline__ short f2bf(float f) {
    union { float f; unsigned int i; } x; x.f = f;
    unsigned int r = x.i + 0x7fffu + ((x.i >> 16) & 1u);
    return (short)(r >> 16);
}

// ---------------- convert f32 -> bf16 (8 elems/thread) ----------------
__global__ __launch_bounds__(256) void cvt_bf16(const float* __restrict__ in,
                                               short* __restrict__ out, int n) {
    int i = (blockIdx.x * 256 + threadIdx.x) * 8;
    if (i >= n) return;
    float4 a = *(const float4*)(in + i);
    float4 b = *(const float4*)(in + i + 4);
    short8 v;
    v[0] = f2bf(a.x); v[1] = f2bf(a.y); v[2] = f2bf(a.z); v[3] = f2bf(a.w);
    v[4] = f2bf(b.x); v[5] = f2bf(b.y); v[6] = f2bf(b.z); v[7] = f2bf(b.w);
    *(short8*)(out + i) = v;
}

// ------------- transpose 4 f32 weights [K][N] -> bf16 [N][K] -------------
__global__ __launch_bounds__(256) void transpose4(
    const float* __restrict__ w0, const float* __restrict__ w1,
    const float* __restrict__ w2, const float* __restrict__ w3,
    short* __restrict__ o0, short* __restrict__ o1,
    short* __restrict__ o2, short* __restrict__ o3)
{
    const float* src; short* dst;
    int z = blockIdx.z;
    if (z == 0)      { src = w0; dst = o0; }
    else if (z == 1) { src = w1; dst = o1; }
    else if (z == 2) { src = w2; dst = o2; }
    else             { src = w3; dst = o3; }
    __shared__ float t[64][65];
    int r0 = blockIdx.y * 64, c0 = blockIdx.x * 64;
    int rd_r = threadIdx.x >> 4, rd_c = (threadIdx.x & 15) * 4;
    #pragma unroll
    for (int it = 0; it < 4; it++) {
        int rr = rd_r + it * 16;
        float4 v = *(const float4*)(src + (size_t)(r0 + rr) * HID + c0 + rd_c);
        t[rr][rd_c + 0] = v.x; t[rr][rd_c + 1] = v.y;
        t[rr][rd_c + 2] = v.z; t[rr][rd_c + 3] = v.w;
    }
    __syncthreads();
    int or_ = threadIdx.x >> 3, oc8 = (threadIdx.x & 7) * 8;
    #pragma unroll
    for (int half = 0; half < 2; half++) {
        int dr = or_ + half * 32;
        short8 v;
        #pragma unroll
        for (int i = 0; i < 8; i++) v[i] = f2bf(t[oc8 + i][dr]);
        *(short8*)(dst + (size_t)(c0 + dr) * HID + r0 + oc8) = v;
    }
}

// ---------------- GEMM: out = X[M,1024](bf16) @ Wt(bf16,[N][K]) + bias(f32) ----
// mode 0/1: q/k with RoPE -> [B,H,S,D] bf16
// mode 2: v -> V^T [B,H,D,S] bf16 (for attn PV B-fragment)
// mode 3: plain row-major [M,N] f32 (final proj)
__global__ __launch_bounds__(256) void gemm_bf16(
    const short* __restrict__ X,
    const short* __restrict__ Wt0,
    const float* __restrict__ b0, const float* __restrict__ b1, const float* __restrict__ b2,
    const float* __restrict__ cosb, const float* __restrict__ sinb,
    short* __restrict__ out0, float* __restrict__ outf,
    int modeBase)
{
    constexpr int LDK = 40;  // 80B row stride
    __shared__ __align__(16) short Asm[128 * LDK];
    __shared__ __align__(16) short Bsm[128 * LDK];
    int z = blockIdx.z;
    int mode = modeBase + z;
    const short* Wt = Wt0 + (size_t)z * HID * HID;
    const float* bias = (z == 0) ? b0 : (z == 1) ? b1 : b2;
    short* outp = out0 + (size_t)z * MDIM * HID;

    int tid = threadIdx.x;
    int lane = tid & 63, wave = tid >> 6;
    int wr = wave >> 1, wc = wave & 1;
    int m0 = blockIdx.x * 128, n0 = blockIdx.y * 128;
    int sr = tid >> 2, sc = (tid & 3) * 8;
    int lr = lane & 15, lg = lane >> 4;

    f32x4 acc[4][4] = {};

    for (int k0 = 0; k0 < HID; k0 += 32) {
        short8 a0  = *(const short8*)(X  + (size_t)(m0 + sr)      * HID + k0 + sc);
        short8 a1  = *(const short8*)(X  + (size_t)(m0 + sr + 64) * HID + k0 + sc);
        short8 w0v = *(const short8*)(Wt + (size_t)(n0 + sr)      * HID + k0 + sc);
        short8 w1v = *(const short8*)(Wt + (size_t)(n0 + sr + 64) * HID + k0 + sc);
        __syncthreads();
        *(short8*)(Asm + sr * LDK + sc) = a0;
        *(short8*)(Asm + (sr + 64) * LDK + sc) = a1;
        *(short8*)(Bsm + sr * LDK + sc) = w0v;
        *(short8*)(Bsm + (sr + 64) * LDK + sc) = w1v;
        __syncthreads();
        short8 af[4], bfr[4];
        #pragma unroll
        for (int m = 0; m < 4; m++)
            af[m] = *(const short8*)(Asm + (wr * 64 + m * 16 + lr) * LDK + lg * 8);
        #pragma unroll
        for (int n = 0; n < 4; n++)
            bfr[n] = *(const short8*)(Bsm + (wc * 64 + n * 16 + lr) * LDK + lg * 8);
        #pragma unroll
        for (int m = 0; m < 4; m++)
            #pragma unroll
            for (int n = 0; n < 4; n++)
                acc[m][n] = __builtin_amdgcn_mfma_f32_16x16x32_bf16(af[m], bfr[n], acc[m][n], 0, 0, 0);
    }

    #pragma unroll
    for (int m = 0; m < 4; m++) {
        #pragma unroll
        for (int n = 0; n < 4; n++) {
            int gr0 = m0 + wr * 64 + m * 16 + lg * 4;
            int gc  = n0 + wc * 64 + n * 16 + lr;
            if (mode == 3) {
                #pragma unroll
                for (int j = 0; j < 4; j++)
                    outf[(size_t)(gr0 + j) * HID + gc] = acc[m][n][j] + bias[gc];
            } else if (mode == 2) {
                // V^T: [B,H,D,S]; 4 consecutive s per lane -> short4 store
                int bb = gr0 >> 11, s0 = gr0 & (SDIM - 1);
                int h = gc >> 6, dd = gc & 63;
                short4v pk;
                #pragma unroll
                for (int j = 0; j < 4; j++) pk[j] = f2bf(acc[m][n][j] + bias[gc]);
                *(short4v*)(outp + ((size_t)((bb * HDIM + h) * DDIM + dd)) * SDIM + s0) = pk;
            } else {
                #pragma unroll
                for (int j = 0; j < 4; j++) {
                    int gr = gr0 + j;
                    int bb = gr >> 11, s = gr & (SDIM - 1);
                    int h = gc >> 6, dd = gc & 63;
                    float v = acc[m][n][j] + bias[gc];
                    // RoPE: partner (even<->odd col) sits in lane^1
                    float p  = __shfl_xor(v, 1);
                    float cc = cosb[s * 32 + (dd >> 1)];
                    float ss = sinb[s * 32 + (dd >> 1)];
                    v = (dd & 1) ? (p * ss + v * cc) : (v * cc - p * ss);
                    outp[((size_t)((bb * HDIM + h) * SDIM + s)) * DDIM + dd] = f2bf(v);
                }
            }
        }
    }
}

// ---------------- causal flash attention ----------------
// Q,K: [B*H, S, D] bf16.  Vt: [B*H, D, S] bf16.  O: [B, S, H, D] bf16.
__global__ __launch_bounds__(256) void attn_fwd(
    const short* __restrict__ Q,
    const short* __restrict__ K,
    const short* __restrict__ Vt,
    short* __restrict__ O)
{
    constexpr int LDK = 72;
    __shared__ __align__(16) short Ks[64 * LDK];
    __shared__ __align__(16) short Vs[64 * LDK];   // V^T tile: [d][kv]
    __shared__ __align__(16) short Ps[4][16 * LDK];
    int qb = gridDim.x - 1 - blockIdx.x;           // heavy blocks first
    int bh = blockIdx.y;
    int tid = threadIdx.x;
    int lane = tid & 63, wave = tid >> 6;
    int lr = lane & 15, lg = lane >> 4;
    const short* qbase  = Q  + ((size_t)bh * SDIM) * DDIM;
    const short* kbase  = K  + ((size_t)bh * SDIM) * DDIM;
    const short* vtbase = Vt + ((size_t)bh * DDIM) * SDIM;

    int qrow = qb * 64 + wave * 16 + lr;
    short8 qf[2];
    qf[0] = *(const short8*)(qbase + (size_t)qrow * DDIM + lg * 8);
    qf[1] = *(const short8*)(qbase + (size_t)qrow * DDIM + 32 + lg * 8);

    float m_run[4], l_run[4];
    #pragma unroll
    for (int j = 0; j < 4; j++) { m_run[j] = -1e30f; l_run[j] = 0.f; }
    f32x4 oacc[4] = {};

    // staging assignment: K rows via (sr_, sc_); Vt rows via (vd_, vq_)
    int sr_ = tid >> 3, sc_ = (tid & 7) * 8;
    int vd_ = tid >> 2, vq_ = (tid & 3) * 16;
    int qr_g = qb * 64 + wave * 16 + lg * 4;

    short8 kreg0, kreg1, vreg0, vreg1;
    {
        const short* kg = kbase;  // kt = 0
        kreg0 = *(const short8*)(kg + (size_t)sr_ * DDIM + sc_);
        kreg1 = *(const short8*)(kg + (size_t)(sr_ + 32) * DDIM + sc_);
        const short* vg = vtbase;
        vreg0 = *(const short8*)(vg + (size_t)vd_ * SDIM + vq_);
        vreg1 = *(const short8*)(vg + (size_t)vd_ * SDIM + vq_ + 8);
    }

    for (int kt = 0; kt <= qb; kt++) {
        __syncthreads();   // prior tile's LDS reads done
        *(short8*)(Ks + sr_ * LDK + sc_) = kreg0;
        *(short8*)(Ks + (sr_ + 32) * LDK + sc_) = kreg1;
        *(short8*)(Vs + vd_ * LDK + vq_) = vreg0;
        *(short8*)(Vs + vd_ * LDK + vq_ + 8) = vreg1;
        __syncthreads();
        if (kt < qb) {  // T14: issue next tile's loads; latency hides under compute
            const short* kg = kbase + (size_t)((kt + 1) * 64) * DDIM;
            kreg0 = *(const short8*)(kg + (size_t)sr_ * DDIM + sc_);
            kreg1 = *(const short8*)(kg + (size_t)(sr_ + 32) * DDIM + sc_);
            const short* vg = vtbase + (kt + 1) * 64;
            vreg0 = *(const short8*)(vg + (size_t)vd_ * SDIM + vq_);
            vreg1 = *(const short8*)(vg + (size_t)vd_ * SDIM + vq_ + 8);
        }

        // QK^T
        f32x4 sf[4] = {};
        #pragma unroll
        for (int n = 0; n < 4; n++) {
            #pragma unroll
            for (int ks = 0; ks < 2; ks++) {
                short8 kf = *(const short8*)(Ks + (n * 16 + lr) * LDK + ks * 32 + lg * 8);
                sf[n] = __builtin_amdgcn_mfma_f32_16x16x32_bf16(qf[ks], kf, sf[n], 0, 0, 0);
            }
        }

        bool diag = (kt == qb);
        #pragma unroll
        for (int j = 0; j < 4; j++) {
            float sv[4];
            float mx = -1e30f;
            if (diag) {
                #pragma unroll
                for (int n = 0; n < 4; n++) {
                    float s = sf[n][j] * 0.125f;
                    int kv_g = kt * 64 + n * 16 + lr;
                    if (kv_g > qr_g + j) s = -1e30f;
                    sv[n] = s;
                    mx = fmaxf(mx, s);
                }
            } else {
                #pragma unroll
                for (int n = 0; n < 4; n++) {
                    float s = sf[n][j] * 0.125f;
                    sv[n] = s;
                    mx = fmaxf(mx, s);
                }
            }
            #pragma unroll
            for (int off = 1; off < 16; off <<= 1) mx = fmaxf(mx, __shfl_xor(mx, off));
            float mnew = fmaxf(m_run[j], mx);
            float scl = __expf(m_run[j] - mnew);
            float lsum = 0.f;
            #pragma unroll
            for (int n = 0; n < 4; n++) {
                float p = __expf(sv[n] - mnew);
                sv[n] = p;
                lsum += p;
            }
            #pragma unroll
            for (int off = 1; off < 16; off <<= 1) lsum += __shfl_xor(lsum, off);
            l_run[j] = l_run[j] * scl + lsum;
            m_run[j] = mnew;
            #pragma unroll
            for (int n = 0; n < 4; n++) {
                oacc[n][j] *= scl;
                Ps[wave][(lg * 4 + j) * LDK + n * 16 + lr] = f2bf(sv[n]);
            }
        }
        // Ps is per-wave: intra-wave LDS dep, no barrier needed

        #pragma unroll
        for (int ks = 0; ks < 2; ks++) {
            short8 pf = *(const short8*)(&Ps[wave][lr * LDK + ks * 32 + lg * 8]);
            #pragma unroll
            for (int n = 0; n < 4; n++) {
                short8 vf = *(const short8*)(Vs + (n * 16 + lr) * LDK + ks * 32 + lg * 8);
                oacc[n] = __builtin_amdgcn_mfma_f32_16x16x32_bf16(pf, vf, oacc[n], 0, 0, 0);
            }
        }
    }

    int b = bh >> 4, h = bh & 15;
    #pragma unroll
    for (int n = 0; n < 4; n++) {
        #pragma unroll
        for (int j = 0; j < 4; j++) {
            int s = qb * 64 + wave * 16 + lg * 4 + j;
            int dd = n * 16 + lr;
            float v = oacc[n][j] / l_run[j];
            O[(((size_t)(b * SDIM + s) * HDIM) + h) * DDIM + dd] = f2bf(v);
        }
    }
}

extern "C" void kernel_launch(void* const* d_in, const int* in_sizes, int n_in,
                              void* d_out, int out_size, void* d_ws, size_t ws_size,
                              hipStream_t stream) {
    const float* x  = (const float*)d_in[0];
    const float* Wq = (const float*)d_in[1];
    const float* bq = (const float*)d_in[2];
    const float* Wk = (const float*)d_in[3];
    const float* bk = (const float*)d_in[4];
    const float* Wv = (const float*)d_in[5];
    const float* bv = (const float*)d_in[6];
    const float* Wo = (const float*)d_in[7];
    const float* bo = (const float*)d_in[8];
    // d_in[9] = mask (causal; computed analytically in-kernel)
    const float* fc = (const float*)d_in[10];
    const float* fs = (const float*)d_in[11];
    float* out = (float*)d_out;
    short* ws  = (short*)d_ws;

    const size_t MM = (size_t)HID * HID;       // 1M elements
    short* xb     = ws;                        // 4*MM  bf16 [M,K]
    short* wt_qkv = ws + 4 * MM;               // 3*MM
    short* wot    = ws + 7 * MM;               // 1*MM
    short* qt     = ws + 8 * MM;               // 4*MM  [B,H,S,D]
    short* ktb    = ws + 12 * MM;              // 4*MM  [B,H,S,D]
    short* vtb    = ws + 16 * MM;              // 4*MM  [B,H,D,S]  (V transposed)
    short* ao     = ws + 20 * MM;              // 4*MM  [B,S,H,D]

    cvt_bf16<<<dim3((MDIM * HID) / (256 * 8)), 256, 0, stream>>>(x, xb, MDIM * HID);
    transpose4<<<dim3(16, 16, 4), 256, 0, stream>>>(Wq, Wk, Wv, Wo,
                                                    wt_qkv, wt_qkv + MM, wt_qkv + 2 * MM, wot);
    gemm_bf16<<<dim3(MDIM / 128, HID / 128, 3), 256, 0, stream>>>(
        xb, wt_qkv, bq, bk, bv, fc, fs, qt, nullptr, 0);
    attn_fwd<<<dim3(SDIM / 64, BDIM * HDIM), 256, 0, stream>>>(qt, ktb, vtb, ao);
    gemm_bf16<<<dim3(MDIM / 128, HID / 128, 1), 256, 0, stream>>>(
        ao, wot, bo, bo, bo, fc, fs, nullptr, out, 3);
}